// Round 10
// baseline (81.756 us; speedup 1.0000x reference)
//
#include <hip/hip_runtime.h>

#define NG 20          // NUM_GAUSSIANS
#define NL 80          // NUM_LETTERS
#define HS 400         // HIDDEN_SIZE
#define ASCALE 0.05f   // ATTENTION_SCALE
#define BB 1024        // B
#define UU 1024        // U
#define LOG2E 1.4426950408889634f

// One block per batch row, 256 threads, single launch.
// r5-r9 post-mortems: exp rate, W L2 traffic, occupancy, and phase-3 work
// were all nulls; counters (VALUBusy 31%, HBM 1.3%, conflicts 0) say the
// ~10us kernel is per-block latency-chain bound. This round shortens the
// chain: NO y0 LDS staging (GEMV reads y0 straight from global; addresses
// are 16-lane-uniform -> wave-broadcast L2 reads), GEMV starts at entry
// with zero upstream deps, 3 barriers instead of 4. Keeps r9's exact
// underflow gate (umax).
__global__ __launch_bounds__(256, 4) void window_fused_kernel(
    const int*   __restrict__ text,    // [B,U]
    const int*   __restrict__ tlen,    // [B]
    const float* __restrict__ y0,      // [B,H]
    const float* __restrict__ prevk,   // [B,N]
    const float* __restrict__ W,       // [3N,H]
    const float* __restrict__ bias,    // [3N]
    float* __restrict__ w_t,           // [B,NL]
    float* __restrict__ k_out,         // [B,NG]
    float* __restrict__ phi_out)       // [B,U]
{
    const int b   = blockIdx.x;
    const int tid = threadIdx.x;

    // prefetch 4 letters/thread + row length (consumed 2 phases later)
    const int4 letters = reinterpret_cast<const int4*>(text + b * UU)[tid];
    const int  len     = tlen[b];

    __shared__ __align__(16) float4 p4s[NG];   // {la, b2, kg, pad}
    __shared__ float wloc[NL];
    __shared__ float umax_s;

    if (tid < NL) wloc[tid] = 0.f;

    // ---- phase 2: 60 linear outputs, 4 lanes each, W AND y0 from global ----
    if (tid < 3 * NG * 4) {                 // 240 active threads
        const int j = tid >> 2;             // output 0..59
        const int p = tid & 3;              // 4-way K split (chunks of 100)
        const float4* wr = reinterpret_cast<const float4*>(W + j * HS + p * 100);
        const float4* yr = reinterpret_cast<const float4*>(y0 + b * HS + p * 100);
        float s = 0.f;
        #pragma unroll 5
        for (int i = 0; i < 25; ++i) {
            const float4 w4 = wr[i];
            const float4 y4 = yr[i];   // 16 lanes share each address -> broadcast
            s += w4.x * y4.x + w4.y * y4.y + w4.z * y4.z + w4.w * y4.w;
        }
        s += __shfl_down(s, 1, 4);
        s += __shfl_down(s, 2, 4);
        if (p == 0) {
            const float val = s + bias[j];
            if (j < NG) {
                p4s[j].x = val * LOG2E;                      // la = log2(a)
            } else if (j < 2 * NG) {
                p4s[j - NG].y = __expf(val) * LOG2E;         // b2 = b*log2e
            } else {
                const int g = j - 2 * NG;
                const float kk = __expf(val) * ASCALE + prevk[b * NG + g];
                p4s[g].z = kk;                               // kg
                k_out[b * NG + g] = kk;
            }
        }
    }
    __syncthreads();   // A: p4s (and wloc zeros) ready

    // ---- phase 2b: block umax = max_n (kg + sqrt(max(la+60,0)/b2)) ----
    if (tid < 32) {
        float reach = -1.f;
        if (tid < NG) {
            const float4 g = p4s[tid];
            const float num = fmaxf(g.x + 60.f, 0.f);
            reach = g.z + __builtin_sqrtf(num / g.y);
        }
        #pragma unroll
        for (int off = 16; off; off >>= 1)
            reach = fmaxf(reach, __shfl_down(reach, off, 32));
        if (tid == 0) umax_s = reach;
    }
    __syncthreads();   // B: umax ready

    // ---- phase 3: 4 consecutive u per thread, underflow-gated ----
    const float umax = umax_s;
    const int u0 = tid * 4;
    float s0 = 0.f, s1 = 0.f, s2 = 0.f, s3 = 0.f;
    if (u0 < len && (float)u0 <= umax) {
        const float uf = (float)u0;
        #pragma unroll
        for (int n = 0; n < NG; ++n) {
            const float4 g = p4s[n];          // b128 broadcast
            const float d0 = g.z - uf;
            const float d1 = d0 - 1.f;
            const float d2 = d0 - 2.f;
            const float d3 = d0 - 3.f;
            s0 += __builtin_amdgcn_exp2f(__builtin_fmaf(-g.y * d0, d0, g.x));
            s1 += __builtin_amdgcn_exp2f(__builtin_fmaf(-g.y * d1, d1, g.x));
            s2 += __builtin_amdgcn_exp2f(__builtin_fmaf(-g.y * d2, d2, g.x));
            s3 += __builtin_amdgcn_exp2f(__builtin_fmaf(-g.y * d3, d3, g.x));
        }
        if (u0 + 1 >= len) s1 = 0.f;
        if (u0 + 2 >= len) s2 = 0.f;
        if (u0 + 3 >= len) s3 = 0.f;
    }
    float4 phi4; phi4.x = s0; phi4.y = s1; phi4.z = s2; phi4.w = s3;
    reinterpret_cast<float4*>(phi_out + b * UU)[tid] = phi4;

    if (s0 != 0.f) atomicAdd(&wloc[letters.x], s0);
    if (s1 != 0.f) atomicAdd(&wloc[letters.y], s1);
    if (s2 != 0.f) atomicAdd(&wloc[letters.z], s2);
    if (s3 != 0.f) atomicAdd(&wloc[letters.w], s3);
    __syncthreads();   // C: wloc complete

    // ---- phase 4: write w_t row ----
    if (tid < NL) w_t[b * NL + tid] = wloc[tid];
}

extern "C" void kernel_launch(void* const* d_in, const int* in_sizes, int n_in,
                              void* d_out, int out_size, void* d_ws, size_t ws_size,
                              hipStream_t stream) {
    const int*   text  = (const int*)  d_in[0];
    const int*   tlen  = (const int*)  d_in[1];
    const float* y0    = (const float*)d_in[2];
    const float* prevk = (const float*)d_in[3];
    const float* W     = (const float*)d_in[4];
    const float* bias  = (const float*)d_in[5];

    float* out   = (float*)d_out;
    float* w_t   = out;                          // [B, NL]
    float* k_out = out + BB * NL;                // [B, NG]
    float* phi   = out + BB * NL + BB * NG;      // [B, U]

    hipLaunchKernelGGL(window_fused_kernel, dim3(BB), dim3(256), 0, stream,
                       text, tlen, y0, prevk, W, bias, w_t, k_out, phi);
}

// Round 11
// 76.224 us; speedup vs baseline: 1.0726x; 1.0726x over previous
//
#include <hip/hip_runtime.h>

#define NG 20          // NUM_GAUSSIANS
#define NL 80          // NUM_LETTERS
#define HS 400         // HIDDEN_SIZE
#define ASCALE 0.05f   // ATTENTION_SCALE
#define BB 1024        // B
#define UU 1024        // U
#define LOG2E 1.4426950408889634f
#define ROWS 4         // batch rows per block

// 256 blocks x 256 threads, 4 rows/block = 1 block per CU.
// r10 lesson: keep y0 LDS staging (global-direct GEMV regressed).
// r6-r9 lessons: exp rate / W-L2 / occupancy / phase-3 work are not the
// bottleneck; the ~10us kernel is per-block latency chains serialized 4-deep
// per CU. This round: one block per CU, W cached in registers ONCE and
// reused for 4 rows' GEMVs, phases batched over rows (4x fewer barriers per
// row), 4 independent row-chains give ILP. Keeps r9's exact underflow gate.
__global__ __launch_bounds__(256) void window_fused4(
    const int*   __restrict__ text,    // [B,U]
    const int*   __restrict__ tlen,    // [B]
    const float* __restrict__ y0,      // [B,H]
    const float* __restrict__ prevk,   // [B,N]
    const float* __restrict__ W,       // [3N,H]
    const float* __restrict__ bias,    // [3N]
    float* __restrict__ w_t,           // [B,NL]
    float* __restrict__ k_out,         // [B,NG]
    float* __restrict__ phi_out)       // [B,U]
{
    const int b0  = blockIdx.x * ROWS;
    const int tid = threadIdx.x;

    // prefetch: 4 rows' letters (int4 each) + lengths, in flight from entry
    int4 letters[ROWS];
    int  len[ROWS];
    #pragma unroll
    for (int r = 0; r < ROWS; ++r) {
        letters[r] = reinterpret_cast<const int4*>(text + (b0 + r) * UU)[tid];
        len[r]     = tlen[b0 + r];
    }

    __shared__ __align__(16) float  yrow[ROWS][HS];
    __shared__ __align__(16) float4 p4s[ROWS][NG];   // {la, b2, kg, pad}
    __shared__ float wloc[ROWS][NL];
    __shared__ float umax_s[ROWS];

    // ---- phase 1: stage 4 y0 rows (400 float4), zero letter bins ----
    for (int i = tid; i < ROWS * HS / 4; i += 256) {
        reinterpret_cast<float4*>(&yrow[0][0])[i] =
            reinterpret_cast<const float4*>(y0 + b0 * HS)[i];
    }
    for (int i = tid; i < ROWS * NL; i += 256) (&wloc[0][0])[i] = 0.f;
    __syncthreads();

    // ---- phase 2: 60 outputs x 4 rows; W slice in registers, loaded once ----
    if (tid < 3 * NG * 4) {                 // 240 active threads
        const int j = tid >> 2;             // output 0..59
        const int p = tid & 3;              // 4-way K split (chunks of 100)
        float4 wreg[25];
        const float4* wr = reinterpret_cast<const float4*>(W + j * HS + p * 100);
        #pragma unroll
        for (int i = 0; i < 25; ++i) wreg[i] = wr[i];
        const float bj = bias[j];

        #pragma unroll
        for (int r = 0; r < ROWS; ++r) {
            const float4* yr = reinterpret_cast<const float4*>(&yrow[r][p * 100]);
            float sa = 0.f, sb = 0.f;       // dual accumulators
            #pragma unroll
            for (int i = 0; i < 25; ++i) {
                const float4 w4 = wreg[i];
                const float4 y4 = yr[i];
                sa += w4.x * y4.x + w4.y * y4.y;
                sb += w4.z * y4.z + w4.w * y4.w;
            }
            float s = sa + sb;
            s += __shfl_down(s, 1, 4);
            s += __shfl_down(s, 2, 4);
            if (p == 0) {
                const int row = b0 + r;
                const float val = s + bj;
                if (j < NG) {
                    p4s[r][j].x = val * LOG2E;                   // la
                } else if (j < 2 * NG) {
                    p4s[r][j - NG].y = __expf(val) * LOG2E;      // b2
                } else {
                    const int g = j - 2 * NG;
                    const float kk = __expf(val) * ASCALE + prevk[row * NG + g];
                    p4s[r][g].z = kk;                            // kg
                    k_out[row * NG + g] = kk;
                }
            }
        }
    }
    __syncthreads();

    // ---- phase 2b: per-row umax = max_n (kg + sqrt(max(la+60,0)/b2)) ----
    if (tid < ROWS * 32) {
        const int r = tid >> 5;
        const int n = tid & 31;
        float reach = -1.f;
        if (n < NG) {
            const float4 g = p4s[r][n];
            reach = g.z + __builtin_sqrtf(fmaxf(g.x + 60.f, 0.f) / g.y);
        }
        #pragma unroll
        for (int off = 16; off; off >>= 1)
            reach = fmaxf(reach, __shfl_down(reach, off, 32));
        if (n == 0) umax_s[r] = reach;
    }
    __syncthreads();

    // ---- phase 3: 4 rows x 4 consecutive u per thread, underflow-gated ----
    const int u0 = tid * 4;
    const float uf = (float)u0;
    #pragma unroll
    for (int r = 0; r < ROWS; ++r) {
        float s0 = 0.f, s1 = 0.f, s2 = 0.f, s3 = 0.f;
        if (u0 < len[r] && uf <= umax_s[r]) {
            #pragma unroll
            for (int n = 0; n < NG; ++n) {
                const float4 g = p4s[r][n];       // b128 broadcast
                const float d0 = g.z - uf;
                const float d1 = d0 - 1.f;
                const float d2 = d0 - 2.f;
                const float d3 = d0 - 3.f;
                s0 += __builtin_amdgcn_exp2f(__builtin_fmaf(-g.y * d0, d0, g.x));
                s1 += __builtin_amdgcn_exp2f(__builtin_fmaf(-g.y * d1, d1, g.x));
                s2 += __builtin_amdgcn_exp2f(__builtin_fmaf(-g.y * d2, d2, g.x));
                s3 += __builtin_amdgcn_exp2f(__builtin_fmaf(-g.y * d3, d3, g.x));
            }
            if (u0 + 1 >= len[r]) s1 = 0.f;
            if (u0 + 2 >= len[r]) s2 = 0.f;
            if (u0 + 3 >= len[r]) s3 = 0.f;
        }
        float4 phi4; phi4.x = s0; phi4.y = s1; phi4.z = s2; phi4.w = s3;
        reinterpret_cast<float4*>(phi_out + (b0 + r) * UU)[tid] = phi4;

        if (s0 != 0.f) atomicAdd(&wloc[r][letters[r].x], s0);
        if (s1 != 0.f) atomicAdd(&wloc[r][letters[r].y], s1);
        if (s2 != 0.f) atomicAdd(&wloc[r][letters[r].z], s2);
        if (s3 != 0.f) atomicAdd(&wloc[r][letters[r].w], s3);
    }
    __syncthreads();

    // ---- phase 4: write 4 w_t rows ----
    if (tid < NL) {
        #pragma unroll
        for (int r = 0; r < ROWS; ++r)
            w_t[(b0 + r) * NL + tid] = wloc[r][tid];
    }
}

extern "C" void kernel_launch(void* const* d_in, const int* in_sizes, int n_in,
                              void* d_out, int out_size, void* d_ws, size_t ws_size,
                              hipStream_t stream) {
    const int*   text  = (const int*)  d_in[0];
    const int*   tlen  = (const int*)  d_in[1];
    const float* y0    = (const float*)d_in[2];
    const float* prevk = (const float*)d_in[3];
    const float* W     = (const float*)d_in[4];
    const float* bias  = (const float*)d_in[5];

    float* out   = (float*)d_out;
    float* w_t   = out;                          // [B, NL]
    float* k_out = out + BB * NL;                // [B, NG]
    float* phi   = out + BB * NL + BB * NG;      // [B, U]

    hipLaunchKernelGGL(window_fused4, dim3(BB / ROWS), dim3(256), 0, stream,
                       text, tlen, y0, prevk, W, bias, w_t, k_out, phi);
}